// Round 15
// baseline (492.461 us; speedup 1.0000x reference)
//
#include <hip/hip_runtime.h>

#define N_NODES 100000
#define N_EDGES 300000
#define N_ETOT  400000   // E + N self-loops
#define NGRAPH  4096
#define HID     128
#define NBLK_SCAN 391    // cdiv(N_NODES, 256)
#define PNPB    32       // nodes per block in pool
#define STATS_BLOCKS 512
#define NSLICE  64       // BN-stats atomic slices

typedef __attribute__((ext_vector_type(8))) short short8;
typedef __attribute__((ext_vector_type(8))) ushort ushort8;
typedef __attribute__((ext_vector_type(4))) float f32x4;

__device__ __forceinline__ ushort f2bf(float f) {
    union { float f; unsigned u; } x; x.f = f;
    unsigned r = x.u + 0x7FFF + ((x.u >> 16) & 1);   // round-to-nearest-even
    return (ushort)(r >> 16);
}

__device__ __forceinline__ float bf2f(ushort v) {
    union { unsigned u; float f; } t;
    t.u = ((unsigned)v) << 16;
    return t.f;
}

// unpack uint holding 2 bf16 (channels 2k, 2k+1) -> float2
__device__ __forceinline__ float2 bf2f2(unsigned v) {
    union { unsigned u; float f; } lo, hi;
    lo.u = v << 16;
    hi.u = v & 0xFFFF0000u;
    return make_float2(lo.f, hi.f);
}

// ---------------- fused setup: weight/x converts + all zero-inits ----------------
__global__ __launch_bounds__(256) void setup_kernel(
    const float* __restrict__ x,
    const float* __restrict__ W1, const float* __restrict__ W2, const float* __restrict__ W3,
    ushort* __restrict__ Wt1, ushort* __restrict__ Wt2, ushort* __restrict__ Wt3,
    ushort* __restrict__ Xb, float* __restrict__ sums_sl, int* __restrict__ counts,
    float* __restrict__ pooled, int* __restrict__ ticket)
{
    const int i = blockIdx.x * 256 + threadIdx.x;
    if (i < 16384) {
        int c = i >> 7, k = i & 127;
        Wt2[c * 128 + k] = f2bf(W2[k * 128 + c]);
    } else if (i < 32768) {
        int j = i - 16384; int c = j >> 7, k = j & 127;
        Wt3[c * 128 + k] = f2bf(W3[k * 128 + c]);
    } else if (i < 36864) {
        int j = i - 32768; int c = j >> 5, k = j & 31;
        Wt1[c * 32 + k] = (k < 22) ? f2bf(W1[k * 128 + c]) : (ushort)0;
    } else if (i < 36864 + N_NODES * 32) {
        int j = i - 36864; int n = j >> 5, k = j & 31;
        Xb[j] = (k < 22) ? f2bf(x[n * 22 + k]) : (ushort)0;
    } else if (i < 36864 + N_NODES * 32 + NSLICE * 256) {
        sums_sl[i - (36864 + N_NODES * 32)] = 0.f;
    } else if (i < 36864 + N_NODES * 32 + NSLICE * 256 + N_NODES) {
        counts[i - (36864 + N_NODES * 32 + NSLICE * 256)] = 0;
    } else if (i < 36864 + N_NODES * 32 + NSLICE * 256 + N_NODES + NGRAPH * HID + NGRAPH) {
        pooled[i - (36864 + N_NODES * 32 + NSLICE * 256 + N_NODES)] = 0.f;
    } else if (i == 36864 + N_NODES * 32 + NSLICE * 256 + N_NODES + NGRAPH * HID + NGRAPH) {
        *ticket = 0;
    }
}
#define SETUP_TOT (36864 + N_NODES * 32 + NSLICE * 256 + N_NODES + NGRAPH * HID + NGRAPH + 1)

// ---------------- GEMM body: Cb[M,128](bf16) = act(A)[M,K]@W + fused scores ----------
// Whole-K staging, XOR-swizzled LDS, one barrier before the MFMA loop.
template<int K, bool PRE_BN, int HH>
__device__ __forceinline__ void gemm_body(
    const ushort* __restrict__ Ab, const ushort* __restrict__ Wt,
    const float* __restrict__ scale, const float* __restrict__ shift,
    const float* __restrict__ avs, const float* __restrict__ avd,
    ushort* __restrict__ Cb, float* __restrict__ als, float* __restrict__ ald,
    int M, int blk)
{
    constexpr int SEGS = K / 8;               // 16B segments per row
    constexpr int SSH  = (K == 128) ? 4 : 2;  // log2(SEGS)
    constexpr int SWM  = SEGS - 1;            // swizzle mask
    constexpr int NP   = SEGS / 2;            // staging passes (256 thr, 128 rows)
    constexpr int KT   = K / 32;              // 32-wide k subtiles

    __shared__ ushort Asm[128 * K];
    __shared__ ushort Bsm[128 * K];

    const int tid  = threadIdx.x;
    const int wave = tid >> 6;
    const int lane = tid & 63;
    const int ln   = lane & 15;
    const int quad = lane >> 4;
    const int wr0  = (wave >> 1) * 64;
    const int wc0  = (wave & 1) * 64;
    const int row0 = blk * 128;

    // ---- staging: issue ALL global loads first (max MLP), then store swizzled ----
    short8 aR[NP], wR[NP];
    #pragma unroll
    for (int q = 0; q < NP; ++q) {
        const int chunk = tid + q * 256;
        const int r   = chunk >> SSH;
        const int seg = chunk & SWM;
        aR[q] = *(const short8*)&Ab[(size_t)(row0 + r) * K + seg * 8];
        wR[q] = *(const short8*)&Wt[(size_t)r * K + seg * 8];
    }
    if constexpr (PRE_BN) {
        #pragma unroll
        for (int q = 0; q < NP; ++q) {
            const int seg = (tid + q * 256) & SWM;
            const int cc  = seg * 8;
            #pragma unroll
            for (int i = 0; i < 8; ++i) {
                float f = bf2f((ushort)aR[q][i]);
                f = fmaxf(f * scale[cc + i] + shift[cc + i], 0.f);
                aR[q][i] = (short)f2bf(f);
            }
        }
    }
    #pragma unroll
    for (int q = 0; q < NP; ++q) {
        const int chunk = tid + q * 256;
        const int r   = chunk >> SSH;
        const int seg = chunk & SWM;
        const int sp  = seg ^ (r & SWM);
        *(short8*)&Asm[r * K + sp * 8] = aR[q];
        *(short8*)&Bsm[r * K + sp * 8] = wR[q];
    }
    __syncthreads();

    // ---- MFMA loop: no barriers, all data LDS-resident ----
    f32x4 acc[4][4] = {};
    #pragma unroll
    for (int kt = 0; kt < KT; ++kt) {
        short8 af[4], bf[4];
        #pragma unroll
        for (int i = 0; i < 4; ++i) {
            const int ra = wr0 + i * 16 + ln;
            const int ca = wc0 + i * 16 + ln;
            af[i] = *(const short8*)&Asm[ra * K + (((kt * 4 + quad) ^ (ra & SWM)) * 8)];
            bf[i] = *(const short8*)&Bsm[ca * K + (((kt * 4 + quad) ^ (ca & SWM)) * 8)];
        }
        #pragma unroll
        for (int tr = 0; tr < 4; ++tr)
            #pragma unroll
            for (int tc = 0; tc < 4; ++tc)
                acc[tr][tc] = __builtin_amdgcn_mfma_f32_16x16x32_bf16(
                    af[tr], bf[tc], acc[tr][tc], 0, 0, 0);
    }

    // ---- C write (bf16; C/D layout: col=lane&15, row=quad*4+reg) ----
    #pragma unroll
    for (int tr = 0; tr < 4; ++tr)
        #pragma unroll
        for (int rg = 0; rg < 4; ++rg) {
            const int gr = row0 + wr0 + tr * 16 + quad * 4 + rg;
            if (gr < M) {
                #pragma unroll
                for (int tc = 0; tc < 4; ++tc)
                    Cb[(size_t)gr * HID + wc0 + tc * 16 + ln] = f2bf(acc[tr][tc][rg]);
            }
        }

    // ---- fused attention scores (ps/pd alias Asm/Bsm after all ds_reads done) ----
    __syncthreads();
    float* ps = (float*)Asm;   // [128][4]
    float* pd = (float*)Bsm;
    #pragma unroll
    for (int tr = 0; tr < 4; ++tr)
      #pragma unroll
      for (int rg = 0; rg < 4; ++rg) {
        float sA = 0.f, sB = 0.f, dA = 0.f, dB = 0.f;
        #pragma unroll
        for (int tc = 0; tc < 4; ++tc) {
            const int col = wc0 + tc * 16 + ln;
            const float v = acc[tr][tc][rg];
            if (tc < 2) { sA += v * avs[col]; dA += v * avd[col]; }
            else        { sB += v * avs[col]; dB += v * avd[col]; }
        }
        #pragma unroll
        for (int m = 1; m < 16; m <<= 1) {
            sA += __shfl_xor(sA, m); sB += __shfl_xor(sB, m);
            dA += __shfl_xor(dA, m); dB += __shfl_xor(dB, m);
        }
        if (ln == 0) {
            const int rl = wr0 + tr * 16 + quad * 4 + rg;
            const int h0 = (wave & 1) * 2;
            ps[rl * 4 + h0] = sA; ps[rl * 4 + h0 + 1] = sB;
            pd[rl * 4 + h0] = dA; pd[rl * 4 + h0 + 1] = dB;
        }
      }
    __syncthreads();
    {
        const int r  = tid & 127;
        const int gr = row0 + r;
        if (gr < M) {
            if (tid < 128) {
                if (HH == 4) {
                    #pragma unroll
                    for (int h = 0; h < 4; ++h) als[gr * 4 + h] = ps[r * 4 + h];
                } else als[gr] = ps[r * 4] + ps[r * 4 + 1] + ps[r * 4 + 2] + ps[r * 4 + 3];
            } else {
                if (HH == 4) {
                    #pragma unroll
                    for (int h = 0; h < 4; ++h) ald[gr * 4 + h] = pd[r * 4 + h];
                } else ald[gr] = pd[r * 4] + pd[r * 4 + 1] + pd[r * 4 + 2] + pd[r * 4 + 3];
            }
        }
    }
}

// standalone GEMM kernel (layers 2, 3)
template<int K, bool PRE_BN, int HH>
__global__ __launch_bounds__(256) void mfma_gemm_kernel(
    const ushort* __restrict__ Ab, const ushort* __restrict__ Wt,
    const float* __restrict__ scale, const float* __restrict__ shift,
    const float* __restrict__ avs, const float* __restrict__ avd,
    ushort* __restrict__ Cb, float* __restrict__ als, float* __restrict__ ald, int M)
{
    gemm_body<K, PRE_BN, HH>(Ab, Wt, scale, shift, avs, avd, Cb, als, ald, M, blockIdx.x);
}

// layer-1 GEMM fused with CSR histogram (independent work, one dispatch)
__global__ __launch_bounds__(256) void gemm1_hist_kernel(
    const ushort* __restrict__ Ab, const ushort* __restrict__ Wt,
    const float* __restrict__ avs, const float* __restrict__ avd,
    ushort* __restrict__ Cb, float* __restrict__ als, float* __restrict__ ald,
    int M, int gemmBlocks, const int* __restrict__ ei, int* __restrict__ counts)
{
    if ((int)blockIdx.x >= gemmBlocks) {
        const int e = (blockIdx.x - gemmBlocks) * 256 + threadIdx.x;
        if (e < N_ETOT) {
            const int dst = (e < N_EDGES) ? ei[N_EDGES + e] : e - N_EDGES;
            atomicAdd(&counts[dst], 1);
        }
        return;
    }
    gemm_body<32, false, 4>(Ab, Wt, nullptr, nullptr, avs, avd, Cb, als, ald, M, blockIdx.x);
}

// ---------------- CSR build ----------------
__global__ __launch_bounds__(256) void scanA_kernel(
    const int* __restrict__ counts, int* __restrict__ rowptr, int* __restrict__ bsum)
{
    __shared__ int ls[256];
    const int t = threadIdx.x;
    const int i = blockIdx.x * 256 + t;
    const int v = (i < N_NODES) ? counts[i] : 0;
    ls[t] = v; __syncthreads();
    #pragma unroll
    for (int off = 1; off < 256; off <<= 1) {
        int add = (t >= off) ? ls[t - off] : 0;
        __syncthreads();
        ls[t] += add;
        __syncthreads();
    }
    if (i < N_NODES) rowptr[i] = ls[t] - v;
    if (t == 255) bsum[blockIdx.x] = ls[255];
}

__global__ __launch_bounds__(512) void scanB_kernel(int* __restrict__ bsum)
{
    __shared__ int ls[512];
    const int t = threadIdx.x;
    const int v = (t < NBLK_SCAN) ? bsum[t] : 0;
    ls[t] = v; __syncthreads();
    #pragma unroll
    for (int off = 1; off < 512; off <<= 1) {
        int add = (t >= off) ? ls[t - off] : 0;
        __syncthreads();
        ls[t] += add;
        __syncthreads();
    }
    if (t < NBLK_SCAN) bsum[t] = ls[t] - v;
}

__global__ void scanC_kernel(int* __restrict__ rowptr, const int* __restrict__ bsum,
                             int* __restrict__ cursor)
{
    int i = blockIdx.x * 256 + threadIdx.x;
    if (i < N_NODES) {
        int v = rowptr[i] + bsum[blockIdx.x];
        rowptr[i] = v;
        cursor[i] = v;
    }
    if (i == 0) rowptr[N_NODES] = N_ETOT;
}

__global__ void scatter_kernel(const int* __restrict__ ei, int* __restrict__ cursor,
                               int* __restrict__ psrc)
{
    int e = blockIdx.x * blockDim.x + threadIdx.x;
    if (e >= N_ETOT) return;
    int src, dst;
    if (e < N_EDGES) { src = ei[e]; dst = ei[N_EDGES + e]; }
    else             { src = dst = e - N_EDGES; }
    int pos = atomicAdd(&cursor[dst], 1);
    psrc[pos] = src;
}

// ---------------- single-pass softmax aggregation (pure; no LDS, no barriers) -------
template<int HH>
__global__ __launch_bounds__(256) void agg_kernel(
    const ushort* __restrict__ H, const float* __restrict__ als,
    const float* __restrict__ ald, const int* __restrict__ rowptr,
    const int* __restrict__ psrc, ushort* __restrict__ Outb)
{
    const int tid  = threadIdx.x;
    const int node = blockIdx.x * 4 + (tid >> 6);   // grid exact: 25000*4 = N_NODES
    const int lane = tid & 63;
    const int grp  = lane >> 4;        // edge slot 0..3
    const int cl   = lane & 15;        // channels 8*cl .. 8*cl+7
    const int hd   = (HH == 4) ? (cl >> 2) : 0;
    const int r0 = rowptr[node];
    const int r1 = rowptr[node + 1];
    const float aldh = (HH == 4) ? ald[node * 4 + hd] : ald[node];

    float den = 0.f;
    float acc[8] = {};
    for (int p = r0 + grp; p < r1; p += 4) {
        const int src = psrc[p];
        float v = ((HH == 4) ? als[src * 4 + hd] : als[src]) + aldh;
        v = (v > 0.f) ? v : 0.2f * v;
        const float ex = __expf(v);
        const uint4 hv = *(const uint4*)&H[(size_t)src * HID + cl * 8];
        const float2 h0 = bf2f2(hv.x), h1 = bf2f2(hv.y);
        const float2 h2 = bf2f2(hv.z), h3 = bf2f2(hv.w);
        acc[0] += ex * h0.x; acc[1] += ex * h0.y;
        acc[2] += ex * h1.x; acc[3] += ex * h1.y;
        acc[4] += ex * h2.x; acc[5] += ex * h2.y;
        acc[6] += ex * h3.x; acc[7] += ex * h3.y;
        den += ex;
    }
    #pragma unroll
    for (int m = 16; m < 64; m <<= 1) {
        den += __shfl_xor(den, m);
        #pragma unroll
        for (int i = 0; i < 8; ++i) acc[i] += __shfl_xor(acc[i], m);
    }
    if (grp == 0) {
        const float inv = 1.f / (den + 1e-16f);
        ushort8 o;
        #pragma unroll
        for (int i = 0; i < 8; ++i) o[i] = f2bf(acc[i] * inv);
        *(ushort8*)&Outb[(size_t)node * HID + cl * 8] = o;
    }
}

// ---------------- BN stats + ticketed last-block finalize ----------------
__global__ __launch_bounds__(256) void bn_stats_kernel(
    const ushort* __restrict__ X, float* __restrict__ sums_sl,
    const float* __restrict__ g, const float* __restrict__ be,
    float* __restrict__ scale, float* __restrict__ shift, int* __restrict__ ticket)
{
    __shared__ float ls[16][128], lq[16][128];   // 16 KB
    __shared__ float red[256];
    __shared__ int lastFlag;
    const int tid = threadIdx.x;
    const int ro  = tid >> 4;         // row slice 0..15
    const int ci  = tid & 15;         // chunk of 8 channels
    const int c0  = ci * 8;
    const int rpb = (N_NODES + STATS_BLOCKS - 1) / STATS_BLOCKS;   // 196
    const int r0  = blockIdx.x * rpb;
    const int r1  = min(r0 + rpb, N_NODES);

    float s[8] = {}, q[8] = {};
    for (int r = r0 + ro; r < r1; r += 16) {
        const ushort8 v = *(const ushort8*)&X[(size_t)r * HID + c0];
        #pragma unroll
        for (int j = 0; j < 8; ++j) {
            const float f = bf2f(v[j]);
            s[j] += f; q[j] += f * f;
        }
    }
    #pragma unroll
    for (int j = 0; j < 8; ++j) { ls[ro][c0 + j] = s[j]; lq[ro][c0 + j] = q[j]; }
    __syncthreads();
    const int half = tid >> 7;
    const int c    = tid & 127;
    float acc = 0.f;
    if (half == 0) {
        #pragma unroll
        for (int k = 0; k < 16; ++k) acc += ls[k][c];
    } else {
        #pragma unroll
        for (int k = 0; k < 16; ++k) acc += lq[k][c];
    }
    atomicAdd(&sums_sl[(blockIdx.x & (NSLICE - 1)) * 256 + tid], acc);
    __threadfence();
    __syncthreads();
    if (tid == 0) lastFlag = (atomicAdd(ticket, 1) == STATS_BLOCKS - 1);
    __syncthreads();
    if (lastFlag) {
        float t = 0.f;
        for (int b = 0; b < NSLICE; ++b) {
            t += __hip_atomic_load(&sums_sl[b * 256 + tid], __ATOMIC_RELAXED,
                                   __HIP_MEMORY_SCOPE_AGENT);
            __hip_atomic_store(&sums_sl[b * 256 + tid], 0.f, __ATOMIC_RELAXED,
                               __HIP_MEMORY_SCOPE_AGENT);
        }
        red[tid] = t;
        __syncthreads();
        if (tid < 128) {
            const float m = red[tid] * (1.f / N_NODES);
            const float v = red[tid + 128] * (1.f / N_NODES) - m * m;
            const float sc = g[tid] * rsqrtf(v + 1e-5f);
            scale[tid] = sc;
            shift[tid] = be[tid] - m * sc;
        }
        if (tid == 0) *ticket = 0;
    }
}

// ---------------- layer-3 BN+ReLU fused pool (run-accumulating; batch sorted) --------
__global__ __launch_bounds__(128) void bn_pool_kernel(
    const ushort* __restrict__ X, const float* __restrict__ scale, const float* __restrict__ shift,
    const int* __restrict__ batch, float* __restrict__ pooled, float* __restrict__ cnt)
{
    const int c = threadIdx.x;
    const int n0 = blockIdx.x * PNPB;
    const int n1 = min(n0 + PNPB, N_NODES);
    const float sc = scale[c], sh = shift[c];
    int gcur = batch[n0];
    float acc = 0.f;
    int run = 0;
    for (int n = n0; n < n1; ++n) {
        const int g = batch[n];
        if (g != gcur) {
            atomicAdd(&pooled[(size_t)gcur * HID + c], acc);
            if (c == 0) atomicAdd(&cnt[gcur], (float)run);
            acc = 0.f; run = 0; gcur = g;
        }
        const float v = bf2f(X[(size_t)n * HID + c]) * sc + sh;
        acc += fmaxf(v, 0.f);
        ++run;
    }
    atomicAdd(&pooled[(size_t)gcur * HID + c], acc);
    if (c == 0) atomicAdd(&cnt[gcur], (float)run);
}

// ---------------- MLP head ----------------
__global__ __launch_bounds__(256) void mlp_kernel(
    const float* __restrict__ pooled, const float* __restrict__ cnt,
    const float* __restrict__ fw1, const float* __restrict__ fb1,
    const float* __restrict__ fw2, const float* __restrict__ fb2,
    float* __restrict__ out)
{
    __shared__ float w1[HID * 64];
    __shared__ float rows[4][HID];
    const int tid = threadIdx.x;
    for (int i = tid; i < HID * 64; i += 256) w1[i] = fw1[i];
    const int gl = tid >> 6;
    const int j  = tid & 63;
    const float b1 = fb1[j];
    const float w2 = fw2[j];
    __syncthreads();
    #pragma unroll
    for (int it = 0; it < 4; ++it) {
        const int g = blockIdx.x * 16 + it * 4 + gl;
        const float inv = 1.f / fmaxf(cnt[g], 1.f);
        rows[gl][j]      = pooled[(size_t)g * HID + j] * inv;
        rows[gl][j + 64] = pooled[(size_t)g * HID + 64 + j] * inv;
        __syncthreads();
        float z = b1;
        #pragma unroll 8
        for (int c2 = 0; c2 < HID; ++c2) z += rows[gl][c2] * w1[c2 * 64 + j];
        z = fmaxf(z, 0.f);
        float p = z * w2;
        #pragma unroll
        for (int off = 32; off; off >>= 1) p += __shfl_down(p, off);
        if (j == 0) out[g] = p + fb2[0];
        __syncthreads();
    }
}

// ---------------- host ----------------
extern "C" void kernel_launch(void* const* d_in, const int* in_sizes, int n_in,
                              void* d_out, int out_size, void* d_ws, size_t ws_size,
                              hipStream_t stream)
{
    const float* x     = (const float*)d_in[0];
    const int*   ei    = (const int*)d_in[1];
    const int*   batch = (const int*)d_in[2];
    const float* W1  = (const float*)d_in[3];
    const float* as1 = (const float*)d_in[4];
    const float* ad1 = (const float*)d_in[5];
    const float* g1  = (const float*)d_in[7];
    const float* be1 = (const float*)d_in[8];
    const float* W2  = (const float*)d_in[9];
    const float* as2 = (const float*)d_in[10];
    const float* ad2 = (const float*)d_in[11];
    const float* g2  = (const float*)d_in[13];
    const float* be2 = (const float*)d_in[14];
    const float* W3  = (const float*)d_in[15];
    const float* as3 = (const float*)d_in[16];
    const float* ad3 = (const float*)d_in[17];
    const float* g3  = (const float*)d_in[19];
    const float* be3 = (const float*)d_in[20];
    const float* fw1 = (const float*)d_in[21];
    const float* fb1 = (const float*)d_in[22];
    const float* fw2 = (const float*)d_in[23];
    const float* fb2 = (const float*)d_in[24];
    float* out = (float*)d_out;

    // ---- ws layout ----
    ushort* Hb  = (ushort*)d_ws;                       // [N][128] bf16 GEMM output
    ushort* Bh  = Hb  + (size_t)N_NODES * HID;         // [N][128] bf16 aggregated
    ushort* Xb  = Bh  + (size_t)N_NODES * HID;         // [N][32]  bf16
    ushort* Wt1 = Xb  + (size_t)N_NODES * 32;          // [128][32]
    ushort* Wt2 = Wt1 + 128 * 32;                      // [128][128]
    ushort* Wt3 = Wt2 + 128 * 128;
    float* als    = (float*)(Wt3 + 128 * 128);
    float* ald    = als + (size_t)N_NODES * 4;
    float* sums_sl= ald + (size_t)N_NODES * 4;         // [NSLICE][256]
    float* scale  = sums_sl + NSLICE * 256;
    float* shift  = scale + HID;
    float* pooled = shift + HID;
    float* cnt    = pooled + (size_t)NGRAPH * HID;     // pooled+cnt contiguous
    int*   rowptr = (int*)(cnt + NGRAPH);
    int*   counts = rowptr + (N_NODES + 1);
    int*   cursor = counts + N_NODES;
    int*   bsum   = cursor + N_NODES;
    int*   ticket = bsum + 512;
    int*   psrc   = ticket + 1;

    auto cdiv = [](int a, int b) { return (a + b - 1) / b; };

    // ---- fused setup (converts + zero-inits + ticket, one dispatch) ----
    setup_kernel<<<cdiv(SETUP_TOT, 256), 256, 0, stream>>>(
        x, W1, W2, W3, Wt1, Wt2, Wt3, Xb, sums_sl, counts, pooled, ticket);

    const int ggrid = cdiv(N_NODES, 128);     // 782
    const int hgrid = cdiv(N_ETOT, 256);      // 1563
    const int agrid = N_NODES / 4;            // 25000, exact

    // ---- layer-1 GEMM (K=32, 4 heads) fused with CSR histogram ----
    gemm1_hist_kernel<<<ggrid + hgrid, 256, 0, stream>>>(
        Xb, Wt1, as1, ad1, Hb, als, ald, N_NODES, ggrid, ei, counts);

    // ---- CSR scan + scatter ----
    scanA_kernel<<<NBLK_SCAN, 256, 0, stream>>>(counts, rowptr, bsum);
    scanB_kernel<<<1, 512, 0, stream>>>(bsum);
    scanC_kernel<<<NBLK_SCAN, 256, 0, stream>>>(rowptr, bsum, cursor);
    scatter_kernel<<<cdiv(N_ETOT, 256), 256, 0, stream>>>(ei, cursor, psrc);

    // ---- layer 1 aggregation + stats ----
    agg_kernel<4><<<agrid, 256, 0, stream>>>(Hb, als, ald, rowptr, psrc, Bh);
    bn_stats_kernel<<<STATS_BLOCKS, 256, 0, stream>>>(Bh, sums_sl, g1, be1, scale, shift, ticket);

    // ---- layer 2: K=128, BN fused into staging, 4 heads ----
    mfma_gemm_kernel<128, true, 4><<<ggrid, 256, 0, stream>>>(
        Bh, Wt2, scale, shift, as2, ad2, Hb, als, ald, N_NODES);
    agg_kernel<4><<<agrid, 256, 0, stream>>>(Hb, als, ald, rowptr, psrc, Bh);
    bn_stats_kernel<<<STATS_BLOCKS, 256, 0, stream>>>(Bh, sums_sl, g2, be2, scale, shift, ticket);

    // ---- layer 3: K=128, BN fused into staging, 1 head ----
    mfma_gemm_kernel<128, true, 1><<<ggrid, 256, 0, stream>>>(
        Bh, Wt3, scale, shift, as3, ad3, Hb, als, ald, N_NODES);
    agg_kernel<1><<<agrid, 256, 0, stream>>>(Hb, als, ald, rowptr, psrc, Bh);
    bn_stats_kernel<<<STATS_BLOCKS, 256, 0, stream>>>(Bh, sums_sl, g3, be3, scale, shift, ticket);

    // ---- BN+ReLU fused pool, then MLP ----
    bn_pool_kernel<<<cdiv(N_NODES, PNPB), 128, 0, stream>>>(Bh, scale, shift, batch, pooled, cnt);
    mlp_kernel<<<NGRAPH / 16, 256, 0, stream>>>(pooled, cnt, fw1, fb1, fw2, fb2, out);
}

// Round 16
// 363.122 us; speedup vs baseline: 1.3562x; 1.3562x over previous
//
#include <hip/hip_runtime.h>

#define N_NODES 100000
#define N_EDGES 300000
#define N_ETOT  400000   // E + N self-loops
#define NGRAPH  4096
#define HID     128
#define NBLK_SCAN 391    // cdiv(N_NODES, 256)
#define PNPB    32       // nodes per block in pool
#define STATS_BLOCKS 512
#define NSLICE  64       // BN-stats atomic slices

typedef __attribute__((ext_vector_type(8))) short short8;
typedef __attribute__((ext_vector_type(8))) ushort ushort8;
typedef __attribute__((ext_vector_type(4))) float f32x4;

__device__ __forceinline__ ushort f2bf(float f) {
    union { float f; unsigned u; } x; x.f = f;
    unsigned r = x.u + 0x7FFF + ((x.u >> 16) & 1);   // round-to-nearest-even
    return (ushort)(r >> 16);
}

__device__ __forceinline__ float bf2f(ushort v) {
    union { unsigned u; float f; } t;
    t.u = ((unsigned)v) << 16;
    return t.f;
}

// unpack uint holding 2 bf16 (channels 2k, 2k+1) -> float2
__device__ __forceinline__ float2 bf2f2(unsigned v) {
    union { unsigned u; float f; } lo, hi;
    lo.u = v << 16;
    hi.u = v & 0xFFFF0000u;
    return make_float2(lo.f, hi.f);
}

// ---------------- fused setup: weight/x converts + all zero-inits ----------------
__global__ __launch_bounds__(256) void setup_kernel(
    const float* __restrict__ x,
    const float* __restrict__ W1, const float* __restrict__ W2, const float* __restrict__ W3,
    ushort* __restrict__ Wt1, ushort* __restrict__ Wt2, ushort* __restrict__ Wt3,
    ushort* __restrict__ Xb, float* __restrict__ sums_sl, int* __restrict__ counts,
    float* __restrict__ pooled)
{
    const int i = blockIdx.x * 256 + threadIdx.x;
    if (i < 16384) {
        int c = i >> 7, k = i & 127;
        Wt2[c * 128 + k] = f2bf(W2[k * 128 + c]);
    } else if (i < 32768) {
        int j = i - 16384; int c = j >> 7, k = j & 127;
        Wt3[c * 128 + k] = f2bf(W3[k * 128 + c]);
    } else if (i < 36864) {
        int j = i - 32768; int c = j >> 5, k = j & 31;
        Wt1[c * 32 + k] = (k < 22) ? f2bf(W1[k * 128 + c]) : (ushort)0;
    } else if (i < 36864 + N_NODES * 32) {
        int j = i - 36864; int n = j >> 5, k = j & 31;
        Xb[j] = (k < 22) ? f2bf(x[n * 22 + k]) : (ushort)0;
    } else if (i < 36864 + N_NODES * 32 + NSLICE * 256) {
        sums_sl[i - (36864 + N_NODES * 32)] = 0.f;
    } else if (i < 36864 + N_NODES * 32 + NSLICE * 256 + N_NODES) {
        counts[i - (36864 + N_NODES * 32 + NSLICE * 256)] = 0;
    } else if (i < 36864 + N_NODES * 32 + NSLICE * 256 + N_NODES + NGRAPH * HID + NGRAPH) {
        pooled[i - (36864 + N_NODES * 32 + NSLICE * 256 + N_NODES)] = 0.f;
    }
}
#define SETUP_TOT (36864 + N_NODES * 32 + NSLICE * 256 + N_NODES + NGRAPH * HID + NGRAPH)

// ---------------- MFMA GEMM: Cb[M,128](bf16) = act(A)[M,K]@W + fused scores ----------
// Whole-K staging: one global->LDS phase (all loads in flight together), XOR-swizzled
// LDS layout (conflict-free reads, no padding), ONE barrier before the MFMA loop.
// ps/pd for the score epilogue alias onto Asm/Bsm after the MFMA loop.
template<int K, bool PRE_BN, int HH>
__global__ __launch_bounds__(256) void mfma_gemm_kernel(
    const ushort* __restrict__ Ab, const ushort* __restrict__ Wt,
    const float* __restrict__ scale, const float* __restrict__ shift,
    const float* __restrict__ avs, const float* __restrict__ avd,
    ushort* __restrict__ Cb, float* __restrict__ als, float* __restrict__ ald, int M)
{
    constexpr int SEGS = K / 8;               // 16B segments per row
    constexpr int SSH  = (K == 128) ? 4 : 2;  // log2(SEGS)
    constexpr int SWM  = SEGS - 1;            // swizzle mask
    constexpr int NP   = SEGS / 2;            // staging passes (256 thr, 128 rows)
    constexpr int KT   = K / 32;              // 32-wide k subtiles

    __shared__ ushort Asm[128 * K];           // K=128: 32 KB each -> 64 KB total
    __shared__ ushort Bsm[128 * K];

    const int tid  = threadIdx.x;
    const int wave = tid >> 6;
    const int lane = tid & 63;
    const int ln   = lane & 15;
    const int quad = lane >> 4;
    const int wr0  = (wave >> 1) * 64;
    const int wc0  = (wave & 1) * 64;
    const int row0 = blockIdx.x * 128;

    // ---- staging: issue ALL global loads first (max MLP), then store swizzled ----
    short8 aR[NP], wR[NP];
    #pragma unroll
    for (int q = 0; q < NP; ++q) {
        const int chunk = tid + q * 256;
        const int r   = chunk >> SSH;
        const int seg = chunk & SWM;
        aR[q] = *(const short8*)&Ab[(size_t)(row0 + r) * K + seg * 8];
        wR[q] = *(const short8*)&Wt[(size_t)r * K + seg * 8];
    }
    if constexpr (PRE_BN) {
        #pragma unroll
        for (int q = 0; q < NP; ++q) {
            const int seg = (tid + q * 256) & SWM;
            const int cc  = seg * 8;
            #pragma unroll
            for (int i = 0; i < 8; ++i) {
                float f = bf2f((ushort)aR[q][i]);
                f = fmaxf(f * scale[cc + i] + shift[cc + i], 0.f);
                aR[q][i] = (short)f2bf(f);
            }
        }
    }
    #pragma unroll
    for (int q = 0; q < NP; ++q) {
        const int chunk = tid + q * 256;
        const int r   = chunk >> SSH;
        const int seg = chunk & SWM;
        const int sp  = seg ^ (r & SWM);
        *(short8*)&Asm[r * K + sp * 8] = aR[q];
        *(short8*)&Bsm[r * K + sp * 8] = wR[q];
    }
    __syncthreads();

    // ---- MFMA loop: no barriers, all data LDS-resident ----
    f32x4 acc[4][4] = {};
    #pragma unroll
    for (int kt = 0; kt < KT; ++kt) {
        short8 af[4], bf[4];
        #pragma unroll
        for (int i = 0; i < 4; ++i) {
            const int ra = wr0 + i * 16 + ln;
            const int ca = wc0 + i * 16 + ln;
            af[i] = *(const short8*)&Asm[ra * K + (((kt * 4 + quad) ^ (ra & SWM)) * 8)];
            bf[i] = *(const short8*)&Bsm[ca * K + (((kt * 4 + quad) ^ (ca & SWM)) * 8)];
        }
        #pragma unroll
        for (int tr = 0; tr < 4; ++tr)
            #pragma unroll
            for (int tc = 0; tc < 4; ++tc)
                acc[tr][tc] = __builtin_amdgcn_mfma_f32_16x16x32_bf16(
                    af[tr], bf[tc], acc[tr][tc], 0, 0, 0);
    }

    // ---- C write (bf16; C/D layout: col=lane&15, row=quad*4+reg) ----
    #pragma unroll
    for (int tr = 0; tr < 4; ++tr)
        #pragma unroll
        for (int rg = 0; rg < 4; ++rg) {
            const int gr = row0 + wr0 + tr * 16 + quad * 4 + rg;
            if (gr < M) {
                #pragma unroll
                for (int tc = 0; tc < 4; ++tc)
                    Cb[(size_t)gr * HID + wc0 + tc * 16 + ln] = f2bf(acc[tr][tc][rg]);
            }
        }

    // ---- fused attention scores (ps/pd alias Asm/Bsm after all ds_reads done) ----
    __syncthreads();
    float* ps = (float*)Asm;   // [128][4]
    float* pd = (float*)Bsm;
    #pragma unroll
    for (int tr = 0; tr < 4; ++tr)
      #pragma unroll
      for (int rg = 0; rg < 4; ++rg) {
        float sA = 0.f, sB = 0.f, dA = 0.f, dB = 0.f;
        #pragma unroll
        for (int tc = 0; tc < 4; ++tc) {
            const int col = wc0 + tc * 16 + ln;
            const float v = acc[tr][tc][rg];
            if (tc < 2) { sA += v * avs[col]; dA += v * avd[col]; }
            else        { sB += v * avs[col]; dB += v * avd[col]; }
        }
        #pragma unroll
        for (int m = 1; m < 16; m <<= 1) {
            sA += __shfl_xor(sA, m); sB += __shfl_xor(sB, m);
            dA += __shfl_xor(dA, m); dB += __shfl_xor(dB, m);
        }
        if (ln == 0) {
            const int rl = wr0 + tr * 16 + quad * 4 + rg;
            const int h0 = (wave & 1) * 2;
            ps[rl * 4 + h0] = sA; ps[rl * 4 + h0 + 1] = sB;
            pd[rl * 4 + h0] = dA; pd[rl * 4 + h0 + 1] = dB;
        }
      }
    __syncthreads();
    {
        const int r  = tid & 127;
        const int gr = row0 + r;
        if (gr < M) {
            if (tid < 128) {
                if (HH == 4) {
                    #pragma unroll
                    for (int h = 0; h < 4; ++h) als[gr * 4 + h] = ps[r * 4 + h];
                } else als[gr] = ps[r * 4] + ps[r * 4 + 1] + ps[r * 4 + 2] + ps[r * 4 + 3];
            } else {
                if (HH == 4) {
                    #pragma unroll
                    for (int h = 0; h < 4; ++h) ald[gr * 4 + h] = pd[r * 4 + h];
                } else ald[gr] = pd[r * 4] + pd[r * 4 + 1] + pd[r * 4 + 2] + pd[r * 4 + 3];
            }
        }
    }
}

// ---------------- CSR build ----------------
__global__ void hist_kernel(const int* __restrict__ ei, int* __restrict__ counts) {
    int e = blockIdx.x * blockDim.x + threadIdx.x;
    if (e >= N_ETOT) return;
    int dst = (e < N_EDGES) ? ei[N_EDGES + e] : e - N_EDGES;
    atomicAdd(&counts[dst], 1);
}

__global__ __launch_bounds__(256) void scanA_kernel(
    const int* __restrict__ counts, int* __restrict__ rowptr, int* __restrict__ bsum)
{
    __shared__ int ls[256];
    const int t = threadIdx.x;
    const int i = blockIdx.x * 256 + t;
    const int v = (i < N_NODES) ? counts[i] : 0;
    ls[t] = v; __syncthreads();
    #pragma unroll
    for (int off = 1; off < 256; off <<= 1) {
        int add = (t >= off) ? ls[t - off] : 0;
        __syncthreads();
        ls[t] += add;
        __syncthreads();
    }
    if (i < N_NODES) rowptr[i] = ls[t] - v;
    if (t == 255) bsum[blockIdx.x] = ls[255];
}

__global__ __launch_bounds__(512) void scanB_kernel(int* __restrict__ bsum)
{
    __shared__ int ls[512];
    const int t = threadIdx.x;
    const int v = (t < NBLK_SCAN) ? bsum[t] : 0;
    ls[t] = v; __syncthreads();
    #pragma unroll
    for (int off = 1; off < 512; off <<= 1) {
        int add = (t >= off) ? ls[t - off] : 0;
        __syncthreads();
        ls[t] += add;
        __syncthreads();
    }
    if (t < NBLK_SCAN) bsum[t] = ls[t] - v;
}

__global__ void scanC_kernel(int* __restrict__ rowptr, const int* __restrict__ bsum,
                             int* __restrict__ cursor)
{
    int i = blockIdx.x * 256 + threadIdx.x;
    if (i < N_NODES) {
        int v = rowptr[i] + bsum[blockIdx.x];
        rowptr[i] = v;
        cursor[i] = v;
    }
    if (i == 0) rowptr[N_NODES] = N_ETOT;
}

__global__ void scatter_kernel(const int* __restrict__ ei, int* __restrict__ cursor,
                               int* __restrict__ psrc)
{
    int e = blockIdx.x * blockDim.x + threadIdx.x;
    if (e >= N_ETOT) return;
    int src, dst;
    if (e < N_EDGES) { src = ei[e]; dst = ei[N_EDGES + e]; }
    else             { src = dst = e - N_EDGES; }
    int pos = atomicAdd(&cursor[dst], 1);
    psrc[pos] = src;
}

// ---------------- single-pass softmax aggregation (pure; no LDS, no barriers) -------
template<int HH>
__global__ __launch_bounds__(256) void agg_kernel(
    const ushort* __restrict__ H, const float* __restrict__ als,
    const float* __restrict__ ald, const int* __restrict__ rowptr,
    const int* __restrict__ psrc, ushort* __restrict__ Outb)
{
    const int tid  = threadIdx.x;
    const int node = blockIdx.x * 4 + (tid >> 6);   // grid exact: 25000*4 = N_NODES
    const int lane = tid & 63;
    const int grp  = lane >> 4;        // edge slot 0..3
    const int cl   = lane & 15;        // channels 8*cl .. 8*cl+7
    const int hd   = (HH == 4) ? (cl >> 2) : 0;
    const int r0 = rowptr[node];
    const int r1 = rowptr[node + 1];
    const float aldh = (HH == 4) ? ald[node * 4 + hd] : ald[node];

    float den = 0.f;
    float acc[8] = {};
    for (int p = r0 + grp; p < r1; p += 4) {
        const int src = psrc[p];
        float v = ((HH == 4) ? als[src * 4 + hd] : als[src]) + aldh;
        v = (v > 0.f) ? v : 0.2f * v;
        const float ex = __expf(v);
        const uint4 hv = *(const uint4*)&H[(size_t)src * HID + cl * 8];
        const float2 h0 = bf2f2(hv.x), h1 = bf2f2(hv.y);
        const float2 h2 = bf2f2(hv.z), h3 = bf2f2(hv.w);
        acc[0] += ex * h0.x; acc[1] += ex * h0.y;
        acc[2] += ex * h1.x; acc[3] += ex * h1.y;
        acc[4] += ex * h2.x; acc[5] += ex * h2.y;
        acc[6] += ex * h3.x; acc[7] += ex * h3.y;
        den += ex;
    }
    #pragma unroll
    for (int m = 16; m < 64; m <<= 1) {
        den += __shfl_xor(den, m);
        #pragma unroll
        for (int i = 0; i < 8; ++i) acc[i] += __shfl_xor(acc[i], m);
    }
    if (grp == 0) {
        const float inv = 1.f / (den + 1e-16f);
        ushort8 o;
        #pragma unroll
        for (int i = 0; i < 8; ++i) o[i] = f2bf(acc[i] * inv);
        *(ushort8*)&Outb[(size_t)node * HID + cl * 8] = o;
    }
}

// ---------------- BN stats: vectorized 16B loads, register accum, sliced atomics ----
__global__ __launch_bounds__(256) void bn_stats_kernel(
    const ushort* __restrict__ X, float* __restrict__ sums_sl)
{
    __shared__ float ls[16][128], lq[16][128];   // 16 KB
    const int tid = threadIdx.x;
    const int ro  = tid >> 4;         // row slice 0..15
    const int ci  = tid & 15;         // chunk of 8 channels
    const int c0  = ci * 8;
    const int rpb = (N_NODES + STATS_BLOCKS - 1) / STATS_BLOCKS;   // 196
    const int r0  = blockIdx.x * rpb;
    const int r1  = min(r0 + rpb, N_NODES);

    float s[8] = {}, q[8] = {};
    for (int r = r0 + ro; r < r1; r += 16) {
        const ushort8 v = *(const ushort8*)&X[(size_t)r * HID + c0];
        #pragma unroll
        for (int j = 0; j < 8; ++j) {
            const float f = bf2f(v[j]);
            s[j] += f; q[j] += f * f;
        }
    }
    #pragma unroll
    for (int j = 0; j < 8; ++j) { ls[ro][c0 + j] = s[j]; lq[ro][c0 + j] = q[j]; }
    __syncthreads();
    const int half = tid >> 7;
    const int c    = tid & 127;
    float acc = 0.f;
    if (half == 0) {
        #pragma unroll
        for (int k = 0; k < 16; ++k) acc += ls[k][c];
    } else {
        #pragma unroll
        for (int k = 0; k < 16; ++k) acc += lq[k][c];
    }
    atomicAdd(&sums_sl[(blockIdx.x & (NSLICE - 1)) * 256 + tid], acc);
}

// reads slice table, computes scale/shift, re-zeroes slices for next layer
__global__ __launch_bounds__(256) void bn_finalize_kernel(
    float* __restrict__ sums_sl,
    const float* __restrict__ g, const float* __restrict__ be,
    float* __restrict__ scale, float* __restrict__ shift)
{
    __shared__ float red[256];
    const int tid = threadIdx.x;
    float s = 0.f;
    for (int b = 0; b < NSLICE; ++b) {
        s += sums_sl[b * 256 + tid];
        sums_sl[b * 256 + tid] = 0.f;
    }
    red[tid] = s;
    __syncthreads();
    if (tid < 128) {
        const float m = red[tid] * (1.f / N_NODES);
        const float v = red[tid + 128] * (1.f / N_NODES) - m * m;
        const float sc = g[tid] * rsqrtf(v + 1e-5f);
        scale[tid] = sc;
        shift[tid] = be[tid] - m * sc;
    }
}

// ---------------- layer-3 BN+ReLU fused pool (run-accumulating; batch sorted) --------
__global__ __launch_bounds__(128) void bn_pool_kernel(
    const ushort* __restrict__ X, const float* __restrict__ scale, const float* __restrict__ shift,
    const int* __restrict__ batch, float* __restrict__ pooled, float* __restrict__ cnt)
{
    const int c = threadIdx.x;
    const int n0 = blockIdx.x * PNPB;
    const int n1 = min(n0 + PNPB, N_NODES);
    const float sc = scale[c], sh = shift[c];
    int gcur = batch[n0];
    float acc = 0.f;
    int run = 0;
    for (int n = n0; n < n1; ++n) {
        const int g = batch[n];
        if (g != gcur) {
            atomicAdd(&pooled[(size_t)gcur * HID + c], acc);
            if (c == 0) atomicAdd(&cnt[gcur], (float)run);
            acc = 0.f; run = 0; gcur = g;
        }
        const float v = bf2f(X[(size_t)n * HID + c]) * sc + sh;
        acc += fmaxf(v, 0.f);
        ++run;
    }
    atomicAdd(&pooled[(size_t)gcur * HID + c], acc);
    if (c == 0) atomicAdd(&cnt[gcur], (float)run);
}

// ---------------- MLP head ----------------
__global__ __launch_bounds__(256) void mlp_kernel(
    const float* __restrict__ pooled, const float* __restrict__ cnt,
    const float* __restrict__ fw1, const float* __restrict__ fb1,
    const float* __restrict__ fw2, const float* __restrict__ fb2,
    float* __restrict__ out)
{
    __shared__ float w1[HID * 64];
    __shared__ float rows[4][HID];
    const int tid = threadIdx.x;
    for (int i = tid; i < HID * 64; i += 256) w1[i] = fw1[i];
    const int gl = tid >> 6;
    const int j  = tid & 63;
    const float b1 = fb1[j];
    const float w2 = fw2[j];
    __syncthreads();
    #pragma unroll
    for (int it = 0; it < 4; ++it) {
        const int g = blockIdx.x * 16 + it * 4 + gl;
        const float inv = 1.f / fmaxf(cnt[g], 1.f);
        rows[gl][j]      = pooled[(size_t)g * HID + j] * inv;
        rows[gl][j + 64] = pooled[(size_t)g * HID + 64 + j] * inv;
        __syncthreads();
        float z = b1;
        #pragma unroll 8
        for (int c2 = 0; c2 < HID; ++c2) z += rows[gl][c2] * w1[c2 * 64 + j];
        z = fmaxf(z, 0.f);
        float p = z * w2;
        #pragma unroll
        for (int off = 32; off; off >>= 1) p += __shfl_down(p, off);
        if (j == 0) out[g] = p + fb2[0];
        __syncthreads();
    }
}

// ---------------- host ----------------
extern "C" void kernel_launch(void* const* d_in, const int* in_sizes, int n_in,
                              void* d_out, int out_size, void* d_ws, size_t ws_size,
                              hipStream_t stream)
{
    const float* x     = (const float*)d_in[0];
    const int*   ei    = (const int*)d_in[1];
    const int*   batch = (const int*)d_in[2];
    const float* W1  = (const float*)d_in[3];
    const float* as1 = (const float*)d_in[4];
    const float* ad1 = (const float*)d_in[5];
    const float* g1  = (const float*)d_in[7];
    const float* be1 = (const float*)d_in[8];
    const float* W2  = (const float*)d_in[9];
    const float* as2 = (const float*)d_in[10];
    const float* ad2 = (const float*)d_in[11];
    const float* g2  = (const float*)d_in[13];
    const float* be2 = (const float*)d_in[14];
    const float* W3  = (const float*)d_in[15];
    const float* as3 = (const float*)d_in[16];
    const float* ad3 = (const float*)d_in[17];
    const float* g3  = (const float*)d_in[19];
    const float* be3 = (const float*)d_in[20];
    const float* fw1 = (const float*)d_in[21];
    const float* fb1 = (const float*)d_in[22];
    const float* fw2 = (const float*)d_in[23];
    const float* fb2 = (const float*)d_in[24];
    float* out = (float*)d_out;

    // ---- ws layout ----
    ushort* Hb  = (ushort*)d_ws;                       // [N][128] bf16 GEMM output
    ushort* Bh  = Hb  + (size_t)N_NODES * HID;         // [N][128] bf16 aggregated
    ushort* Xb  = Bh  + (size_t)N_NODES * HID;         // [N][32]  bf16
    ushort* Wt1 = Xb  + (size_t)N_NODES * 32;          // [128][32]
    ushort* Wt2 = Wt1 + 128 * 32;                      // [128][128]
    ushort* Wt3 = Wt2 + 128 * 128;
    float* als    = (float*)(Wt3 + 128 * 128);
    float* ald    = als + (size_t)N_NODES * 4;
    float* sums_sl= ald + (size_t)N_NODES * 4;         // [NSLICE][256]
    float* scale  = sums_sl + NSLICE * 256;
    float* shift  = scale + HID;
    float* pooled = shift + HID;
    float* cnt    = pooled + (size_t)NGRAPH * HID;     // pooled+cnt contiguous
    int*   rowptr = (int*)(cnt + NGRAPH);
    int*   counts = rowptr + (N_NODES + 1);
    int*   cursor = counts + N_NODES;
    int*   bsum   = cursor + N_NODES;
    int*   psrc   = bsum + 512;

    auto cdiv = [](int a, int b) { return (a + b - 1) / b; };

    // ---- fused setup (converts + zero-inits, one dispatch) ----
    setup_kernel<<<cdiv(SETUP_TOT, 256), 256, 0, stream>>>(
        x, W1, W2, W3, Wt1, Wt2, Wt3, Xb, sums_sl, counts, pooled);

    // ---- CSR build (once) ----
    hist_kernel<<<cdiv(N_ETOT, 256), 256, 0, stream>>>(ei, counts);
    scanA_kernel<<<NBLK_SCAN, 256, 0, stream>>>(counts, rowptr, bsum);
    scanB_kernel<<<1, 512, 0, stream>>>(bsum);
    scanC_kernel<<<NBLK_SCAN, 256, 0, stream>>>(rowptr, bsum, cursor);
    scatter_kernel<<<cdiv(N_ETOT, 256), 256, 0, stream>>>(ei, cursor, psrc);

    const int ggrid = cdiv(N_NODES, 128);
    const int agrid = N_NODES / 4;   // 25000, exact

    // ---- layer 1: K=32 (padded), 4 heads ----
    mfma_gemm_kernel<32, false, 4><<<ggrid, 256, 0, stream>>>(
        Xb, Wt1, nullptr, nullptr, as1, ad1, Hb, als, ald, N_NODES);
    agg_kernel<4><<<agrid, 256, 0, stream>>>(Hb, als, ald, rowptr, psrc, Bh);
    bn_stats_kernel<<<STATS_BLOCKS, 256, 0, stream>>>(Bh, sums_sl);
    bn_finalize_kernel<<<1, 256, 0, stream>>>(sums_sl, g1, be1, scale, shift);

    // ---- layer 2: K=128, BN fused into staging, 4 heads ----
    mfma_gemm_kernel<128, true, 4><<<ggrid, 256, 0, stream>>>(
        Bh, Wt2, scale, shift, as2, ad2, Hb, als, ald, N_NODES);
    agg_kernel<4><<<agrid, 256, 0, stream>>>(Hb, als, ald, rowptr, psrc, Bh);
    bn_stats_kernel<<<STATS_BLOCKS, 256, 0, stream>>>(Bh, sums_sl);
    bn_finalize_kernel<<<1, 256, 0, stream>>>(sums_sl, g2, be2, scale, shift);

    // ---- layer 3: K=128, BN fused into staging, 1 head ----
    mfma_gemm_kernel<128, true, 1><<<ggrid, 256, 0, stream>>>(
        Bh, Wt3, scale, shift, as3, ad3, Hb, als, ald, N_NODES);
    agg_kernel<1><<<agrid, 256, 0, stream>>>(Hb, als, ald, rowptr, psrc, Bh);
    bn_stats_kernel<<<STATS_BLOCKS, 256, 0, stream>>>(Bh, sums_sl);
    bn_finalize_kernel<<<1, 256, 0, stream>>>(sums_sl, g3, be3, scale, shift);

    // ---- BN+ReLU fused pool, then MLP ----
    bn_pool_kernel<<<cdiv(N_NODES, PNPB), 128, 0, stream>>>(Bh, scale, shift, batch, pooled, cnt);
    mlp_kernel<<<NGRAPH / 16, 256, 0, stream>>>(pooled, cnt, fw1, fb1, fw2, fb2, out);
}